// Round 11
// baseline (1353.363 us; speedup 1.0000x reference)
//
#include <hip/hip_runtime.h>
#include <hip/hip_bf16.h>

#define D_MODEL 4096
#define D_FF    11008
#define NTOK    4096   // 2 * 2048 tokens

typedef unsigned int u32;
typedef unsigned short u16;
using f32x4   = __attribute__((ext_vector_type(4))) float;
using bf16x8  = __attribute__((ext_vector_type(8))) short;
using ushort8 = __attribute__((ext_vector_type(8))) unsigned short;
using int4v   = __attribute__((ext_vector_type(4))) int;
using float4v = __attribute__((ext_vector_type(4))) float;

__device__ __forceinline__ u16 bf16_rn(float f) {
    u32 u = __builtin_bit_cast(u32, f);
    u += 0x7FFFu + ((u >> 16) & 1u);
    return (u16)(u >> 16);
}
__device__ __forceinline__ u16 bf16_from_int(int v) {
    float f = (float)v;   // exact for |v| <= 127
    return (u16)(__builtin_bit_cast(u32, f) >> 16);
}
__device__ __forceinline__ void gload16(const void* g, void* l) {
    __builtin_amdgcn_global_load_lds(
        (const __attribute__((address_space(1))) u32*)g,
        (__attribute__((address_space(3))) u32*)l, 16, 0, 0);
}

// ---------------- x fp32 -> bf16 ----------------
__global__ void k_cvt_x(const float* __restrict__ x, u16* __restrict__ xb) {
    int i = (blockIdx.x * 256 + threadIdx.x) * 8;
    float4v a = *(const float4v*)(x + i);
    float4v b = *(const float4v*)(x + i + 4);
    ushort8 o;
    o[0] = bf16_rn(a[0]); o[1] = bf16_rn(a[1]); o[2] = bf16_rn(a[2]); o[3] = bf16_rn(a[3]);
    o[4] = bf16_rn(b[0]); o[5] = bf16_rn(b[1]); o[6] = bf16_rn(b[2]); o[7] = bf16_rn(b[3]);
    *(ushort8*)(xb + i) = o;
}

// ---------------- weight int32 -> bf16 ----------------
__global__ void k_cvt_w(const int* __restrict__ w, u16* __restrict__ wb, int n) {
    int i = (blockIdx.x * 256 + threadIdx.x) * 8;
    if (i >= n) return;
    int4v a = *(const int4v*)(w + i);
    int4v b = *(const int4v*)(w + i + 4);
    ushort8 o;
    o[0] = bf16_from_int(a[0]); o[1] = bf16_from_int(a[1]);
    o[2] = bf16_from_int(a[2]); o[3] = bf16_from_int(a[3]);
    o[4] = bf16_from_int(b[0]); o[5] = bf16_from_int(b[1]);
    o[6] = bf16_from_int(b[2]); o[7] = bf16_from_int(b[3]);
    *(ushort8*)(wb + i) = o;
}

// =====================================================================
// 256x128 GEMM, BK=32, ONE phase per K-tile, 48 KiB LDS double-buffer
// -> 2 blocks/CU (TLP hides the per-phase vmcnt(0)/barrier stalls that
// capped the 1-block/CU 256x256 variant at MfmaUtil 45%).
// 8 waves = 4M x 2N, wave tile 64x64 (acc 64 VGPR), launch_bounds(512,4)
// forces <=128 VGPR so 2 blocks fit.
// LDS layout: row-PAIR grouping [pair][2 rows][32 elems] -> 128B pair
// stride keeps the proven 8-way XOR swizzle conflict-free at BK=32.
// Stage source is pre-swizzled (s = sub ^ (pair&7) involution, both
// sides). Per phase: 8 ds_read_b128 + 3 gload_lds + lgkm(0) + 16 MFMA
// + vmcnt(0) + 1 barrier. WAR: phase t stages buf (t+1)&1 whose readers
// drained at phase t-1's lgkm+barrier. RAW: vmcnt(0)+barrier at phase
// end completes tile t+1 before phase t+1 reads it.
// EPI: 3 = fused gate+up: B-tile rows = [gate32|up32|gate32|up32] of a
//          64-f-col block -> acc[m][0,1]=gate pairs acc[m][2,3]=up;
//          obf = bf16( silu(g*gs) * (u*us) )
//      2 = down: B-tile = 128 rows of dw; of32 = acc*scale
// =====================================================================

#define DSR(dst, addr, IMM)                                                   \
  asm volatile("ds_read_b128 %0, %1 offset:%c2"                               \
               : "=v"(dst) : "v"(addr), "i"(IMM))

#define BAR   __builtin_amdgcn_s_barrier()
#define SB0   __builtin_amdgcn_sched_barrier(0)
#define PRIO1 __builtin_amdgcn_s_setprio(1)
#define PRIO0 __builtin_amdgcn_s_setprio(0)
#define VMC(N)  asm volatile("s_waitcnt vmcnt(" #N ")" ::: "memory")
#define LGKM(N) asm volatile("s_waitcnt lgkmcnt(" #N ")" ::: "memory")

// LDS (u16 elems): A: buf*8192 (+4096 = rows 128..255), B: 16384 + buf*4096
#define STAGE(BUF, K0) {                                                      \
  gload16(a_src0 + (K0), &lds[(BUF)*8192 + wave*512]);                        \
  gload16(a_src1 + (K0), &lds[(BUF)*8192 + 4096 + wave*512]);                 \
  gload16(b_src  + (K0), &lds[16384 + (BUF)*4096 + wave*512]); }

#define PHASE(CUR, T) {                                                       \
  DSR(a[0], adA, (CUR)*16384 + 0);                                            \
  DSR(a[1], adA, (CUR)*16384 + 1024);                                         \
  DSR(a[2], adA, (CUR)*16384 + 2048);                                         \
  DSR(a[3], adA, (CUR)*16384 + 3072);                                         \
  DSR(b[0], adB, (CUR)*8192 + 0);                                             \
  DSR(b[1], adB, (CUR)*8192 + 1024);                                          \
  DSR(b[2], adB, (CUR)*8192 + 2048);                                          \
  DSR(b[3], adB, (CUR)*8192 + 3072);                                          \
  if ((T)+1 < nt) STAGE((CUR)^1, ((T)+1)*32);                                 \
  LGKM(0); SB0; PRIO1;                                                        \
  _Pragma("unroll") for (int mm = 0; mm < 4; ++mm)                            \
  _Pragma("unroll") for (int nn = 0; nn < 4; ++nn)                            \
    acc[mm][nn] = __builtin_amdgcn_mfma_f32_16x16x32_bf16(                    \
        a[mm], b[nn], acc[mm][nn], 0, 0, 0);                                  \
  PRIO0;                                                                      \
  if ((T)+1 < nt) VMC(0);                                                     \
  BAR; }

template<int EPI>
__global__ __launch_bounds__(512, 4) void k_gemm(
    const u16* __restrict__ A,
    const u16* __restrict__ B0, const u16* __restrict__ B1,
    const float* __restrict__ sc0, const float* __restrict__ sc1,
    u16* __restrict__ obf, float* __restrict__ of32,
    int K, int NBN, int ldc)
{
    __shared__ __align__(16) u16 lds[24576];   // 48 KiB

    const int tid  = threadIdx.x;
    const int lane = tid & 63;
    const int wave = tid >> 6;          // 0..7
    const int wm   = wave >> 1;         // 0..3 (64-row block)
    const int wn   = wave & 1;          // 0..1 (64-col block)

    // XCD-aware bijective swizzle (m204); bm slow, bn fast (R10)
    const int nwg  = 16 * NBN;
    const int orig = blockIdx.x;
    const int qq   = nwg >> 3, rr = nwg & 7;
    const int xcd  = orig & 7;
    const int swz  = (xcd < rr ? xcd*(qq+1) : rr*(qq+1) + (xcd-rr)*qq) + (orig >> 3);
    const int bm   = swz / NBN;
    const int bn   = swz % NBN;

    // ---- fragment-read addresses (row-pair layout, 8-way XOR swizzle)
    const int r    = lane & 15;
    const int sQ   = lane >> 4;         // 0..3 (k-granule)
    const int sw16 = (((r & 1) * 4 + sQ) ^ ((r >> 1) & 7)) * 16;  // bytes
    const u32 lbase = (u32)(uintptr_t)(__attribute__((address_space(3))) u16*)&lds[0];
    const u32 adA = lbase + wm*4096 + (r >> 1)*128 + sw16;           // + m*1024 + buf*16384
    const u32 adB = lbase + 32768 + wn*4096 + (r >> 1)*128 + sw16;   // + n*1024 + buf*8192

    // ---- stage sources (inverse swizzle on the global address)
    const int l3  = lane >> 3;               // 0..7
    const int s   = (lane & 7) ^ l3;         // involution
    const int srw = wave*16 + l3*2 + (s >> 2);   // [0,128)
    const int sk8 = (s & 3) * 8;                 // k offset (elems)
    const u16* a_src0 = A + (size_t)(bm*256 + srw) * K + sk8;
    const u16* a_src1 = a_src0 + (size_t)128 * K;
    const u16* b_src;
    if constexpr (EPI == 3) {
        const int q  = srw >> 5, rb = srw & 31;
        const int f  = bn*64 + (q >> 1)*32 + rb;
        b_src = ((q & 1) ? B1 : B0) + (size_t)f * K + sk8;
    } else {
        b_src = B0 + (size_t)(bn*128 + srw) * K + sk8;
    }

    f32x4 acc[4][4];
#pragma unroll
    for (int m = 0; m < 4; ++m)
#pragma unroll
        for (int n = 0; n < 4; ++n) acc[m][n] = (f32x4){0.f, 0.f, 0.f, 0.f};

    const int nt = K >> 5;              // K/32: 128 (K=4096) or 344 (K=11008), even

    // ---- prologue: tile0 -> buf0
    STAGE(0, 0);
    VMC(0);
    BAR;

    bf16x8 a[4], b[4];
    for (int t = 0; t < nt; t += 2) {
        PHASE(0, t);
        PHASE(1, t + 1);
    }

    // ---- epilogue
    if constexpr (EPI == 3) {
#pragma unroll
        for (int n = 0; n < 2; ++n) {
            const int f = bn*64 + wn*32 + n*16 + r;
            const float gsc = sc0[f];
            const float usc = sc1[f];
#pragma unroll
            for (int m = 0; m < 4; ++m) {
                const int row = bm*256 + wm*64 + m*16 + sQ*4;
#pragma unroll
                for (int q2 = 0; q2 < 4; ++q2) {
                    const float g = acc[m][n][q2] * gsc;
                    const float u = acc[m][n+2][q2] * usc;
                    const float s2 = g / (1.0f + __expf(-g));
                    obf[(size_t)(row + q2) * ldc + f] = bf16_rn(s2 * u);
                }
            }
        }
    } else {
#pragma unroll
        for (int n = 0; n < 4; ++n) {
            const int col = bn*128 + wn*64 + n*16 + r;
            const float dsc = sc0[col];
#pragma unroll
            for (int m = 0; m < 4; ++m) {
                const int row = bm*256 + wm*64 + m*16 + sQ*4;
#pragma unroll
                for (int q2 = 0; q2 < 4; ++q2)
                    of32[(size_t)(row + q2) * ldc + col] = acc[m][n][q2] * dsc;
            }
        }
    }
}

extern "C" void kernel_launch(void* const* d_in, const int* in_sizes, int n_in,
                              void* d_out, int out_size, void* d_ws, size_t ws_size,
                              hipStream_t stream) {
    const float* x  = (const float*)d_in[0];
    const int*   gw = (const int*)d_in[1];
    const float* gs = (const float*)d_in[2];
    const int*   uw = (const int*)d_in[3];
    const float* us = (const float*)d_in[4];
    const int*   dw = (const int*)d_in[5];
    const float* ds = (const float*)d_in[6];
    float* out = (float*)d_out;

    const size_t XB = (size_t)NTOK * D_MODEL * 2;   // 33.5 MB  x bf16
    const size_t WB = (size_t)D_FF * D_MODEL * 2;   // 90.2 MB  weight bf16
    const size_t HB = (size_t)NTOK * D_FF * 2;      // 90.2 MB  h bf16
    if (ws_size < XB + 2 * WB + HB) return;         // loud failure (poisoned out)

    char* ws = (char*)d_ws;
    u16* xb  = (u16*)ws;
    u16* wbG = (u16*)(ws + XB);
    u16* wbU = (u16*)(ws + XB + WB);
    u16* hb  = (u16*)(ws + XB + 2 * WB);

    const int wn_elems = D_FF * D_MODEL;            // 45,088,768
    const int wgrid = wn_elems / (8 * 256);

    k_cvt_x<<<(NTOK * D_MODEL) / (8 * 256), 256, 0, stream>>>(x, xb);
    k_cvt_w<<<wgrid, 256, 0, stream>>>(gw, wbG, wn_elems);
    k_cvt_w<<<wgrid, 256, 0, stream>>>(uw, wbU, wn_elems);

    // fused: h = bf16( silu((xb.gw^T)*gs) * (xb.uw^T)*us )
    k_gemm<3><<<16 * (D_FF / 64), 512, 0, stream>>>(
        xb, wbG, wbU, gs, us, hb, nullptr, D_MODEL, D_FF / 64, D_FF);

    // down: out = (h . dw^T) * ds   (reuse gate-weight buffer)
    k_cvt_w<<<wgrid, 256, 0, stream>>>(dw, wbG, wn_elems);
    k_gemm<2><<<16 * (D_MODEL / 128), 512, 0, stream>>>(
        hb, wbG, wbG, ds, nullptr, nullptr, out, D_FF, D_MODEL / 128, D_MODEL);
}

// Round 12
// 1122.899 us; speedup vs baseline: 1.2052x; 1.2052x over previous
//
#include <hip/hip_runtime.h>
#include <hip/hip_bf16.h>

#define D_MODEL 4096
#define D_FF    11008
#define NTOK    4096   // 2 * 2048 tokens

typedef unsigned int u32;
typedef unsigned short u16;
using f32x4   = __attribute__((ext_vector_type(4))) float;
using bf16x8  = __attribute__((ext_vector_type(8))) short;
using ushort8 = __attribute__((ext_vector_type(8))) unsigned short;
using int4v   = __attribute__((ext_vector_type(4))) int;
using float4v = __attribute__((ext_vector_type(4))) float;

__device__ __forceinline__ u16 bf16_rn(float f) {
    u32 u = __builtin_bit_cast(u32, f);
    u += 0x7FFFu + ((u >> 16) & 1u);
    return (u16)(u >> 16);
}
__device__ __forceinline__ u16 bf16_from_int(int v) {
    float f = (float)v;   // exact for |v| <= 127
    return (u16)(__builtin_bit_cast(u32, f) >> 16);
}
__device__ __forceinline__ float bf16_to_f(u16 b) {
    u32 u = (u32)b << 16;
    return __builtin_bit_cast(float, u);
}
__device__ __forceinline__ void gload16(const void* g, void* l) {
    __builtin_amdgcn_global_load_lds(
        (const __attribute__((address_space(1))) u32*)g,
        (__attribute__((address_space(3))) u32*)l, 16, 0, 0);
}

// ---------------- x fp32 -> bf16 ----------------
__global__ void k_cvt_x(const float* __restrict__ x, u16* __restrict__ xb) {
    int i = (blockIdx.x * 256 + threadIdx.x) * 8;
    float4v a = *(const float4v*)(x + i);
    float4v b = *(const float4v*)(x + i + 4);
    ushort8 o;
    o[0] = bf16_rn(a[0]); o[1] = bf16_rn(a[1]); o[2] = bf16_rn(a[2]); o[3] = bf16_rn(a[3]);
    o[4] = bf16_rn(b[0]); o[5] = bf16_rn(b[1]); o[6] = bf16_rn(b[2]); o[7] = bf16_rn(b[3]);
    *(ushort8*)(xb + i) = o;
}

// ---------------- weight int32 -> bf16 ----------------
__global__ void k_cvt_w(const int* __restrict__ w, u16* __restrict__ wb, int n) {
    int i = (blockIdx.x * 256 + threadIdx.x) * 8;
    if (i >= n) return;
    int4v a = *(const int4v*)(w + i);
    int4v b = *(const int4v*)(w + i + 4);
    ushort8 o;
    o[0] = bf16_from_int(a[0]); o[1] = bf16_from_int(a[1]);
    o[2] = bf16_from_int(a[2]); o[3] = bf16_from_int(a[3]);
    o[4] = bf16_from_int(b[0]); o[5] = bf16_from_int(b[1]);
    o[6] = bf16_from_int(b[2]); o[7] = bf16_from_int(b[3]);
    *(ushort8*)(wb + i) = o;
}

// =====================================================================
// 256x256 GEMM, 2 phases/K-tile. R12 change vs R10: fragment reads are
// COMPILER-VISIBLE C++ loads (no inline-asm ds_read, no lgkmcnt(0)
// wall, no sched_barrier) -> the compiler emits fine-grained counted
// lgkmcnt per MFMA so LDS reads overlap MFMA instead of serializing
// (the m97/m201-proven behavior; the asm wall was the 45%-MfmaUtil cap).
// WAR safety: every read is consumed by an MFMA in its own phase, so
// reads complete (operand dep) before the phase's closing barrier;
// staging DMA for a region issues >= 1 barrier after its readers.
// RAW: vmcnt(6) at Ph2 end drains the entire next-tile buffer (R8 FIFO
// audit). 8 waves (2Mx4N), BK=64, dbuf 128 KiB LDS, XOR-granule
// swizzle, gload_lds staging (pre-swizzled source), setprio.
// EPI: 3 = fused gate+up (B0=gate rows, B1=up rows, same f-cols)
//      2 = down (of32 = acc*scale)
// =====================================================================

// element offsets: A(buf,h) = buf*32768 + h*8192; B adds +16384
#define READA(AA, BUF, MH) {                                                  \
  _Pragma("unroll") for (int mm = 0; mm < 4; ++mm) {                          \
    AA[mm][0] = *(const bf16x8*)&lds[(BUF)*32768 + (MH)*8192 + mm*1024 + aoffE + g0E]; \
    AA[mm][1] = *(const bf16x8*)&lds[(BUF)*32768 + (MH)*8192 + mm*1024 + aoffE + g1E]; } }

#define READB(BB, BUF, NH) {                                                  \
  _Pragma("unroll") for (int nn = 0; nn < 2; ++nn) {                          \
    BB[nn][0] = *(const bf16x8*)&lds[(BUF)*32768 + 16384 + (NH)*8192 + nn*1024 + boffE + g0E]; \
    BB[nn][1] = *(const bf16x8*)&lds[(BUF)*32768 + 16384 + (NH)*8192 + nn*1024 + boffE + g1E]; } }

#define MFMA16(MH, NH, AA, BB)                                                \
  _Pragma("unroll") for (int mm = 0; mm < 4; ++mm)                            \
  _Pragma("unroll") for (int nn = 0; nn < 2; ++nn)                            \
  _Pragma("unroll") for (int kk = 0; kk < 2; ++kk)                            \
    acc[(MH)*4+mm][(NH)*2+nn] = __builtin_amdgcn_mfma_f32_16x16x32_bf16(      \
        AA[mm][kk], BB[nn][kk], acc[(MH)*4+mm][(NH)*2+nn], 0, 0, 0);

// LDS element offsets for staging (ushort units)
#define REGA(BUF, H) ((BUF)*32768 + (H)*8192)
#define REGB(BUF, H) ((BUF)*32768 + 16384 + (H)*8192)

#define STAGE_A(BUF, MH, K0) {                                                \
  const u16* _s = A + a_sbase + (size_t)(MH)*128*K + (K0);                    \
  gload16(_s,                &lds[REGA(BUF, MH) + wave*512]);                 \
  gload16(_s + (size_t)64*K, &lds[REGA(BUF, MH) + (8+wave)*512]); }

// NH is a literal 0/1 at every use -> base select folds at compile time
#define STAGE_B(BUF, NH, K0) {                                                \
  const u16* _s = ((NH) ? b1base : b0base) + (K0);                            \
  gload16(_s,                &lds[REGB(BUF, NH) + wave*512]);                 \
  gload16(_s + (size_t)64*K, &lds[REGB(BUF, NH) + (8+wave)*512]); }

#define BAR   __builtin_amdgcn_s_barrier()
#define PRIO1 __builtin_amdgcn_s_setprio(1)
#define PRIO0 __builtin_amdgcn_s_setprio(0)
#define VMC(N)  asm volatile("s_waitcnt vmcnt(" #N ")" ::: "memory")

#define TILE2(CUR, NXT, T) {                                                  \
  /* Ph1: read a0,b0,b1 of CUR; stage A(T+1)h1 -> NXT; MFMA Q1,Q2 */          \
  READA(a0, CUR, 0); READB(b0, CUR, 0); READB(b1, CUR, 1);                    \
  if ((T)+1 < nt) STAGE_A(NXT, 1, ((T)+1) << 6);                              \
  BAR; PRIO1;                                                                 \
  MFMA16(0, 0, a0, b0); MFMA16(0, 1, a0, b1);                                 \
  PRIO0; BAR;                                                                 \
  /* Ph2: read a1 of CUR; stage A(T+2)h0,B(T+2)h0,B(T+2)h1 -> CUR */          \
  READA(a1, CUR, 1);                                                          \
  if ((T)+2 < nt) { STAGE_A(CUR, 0, ((T)+2) << 6);                            \
                    STAGE_B(CUR, 0, ((T)+2) << 6);                            \
                    STAGE_B(CUR, 1, ((T)+2) << 6); }                          \
  BAR; PRIO1;                                                                 \
  MFMA16(1, 1, a1, b1); MFMA16(1, 0, a1, b0);                                 \
  PRIO0;                                                                      \
  if ((T)+2 < nt) { VMC(6); } else { VMC(0); }                                \
  BAR; }

template<int EPI>
__global__ __launch_bounds__(512, 2) void k_gemm256(
    const u16* __restrict__ A,
    const u16* __restrict__ B0, const u16* __restrict__ B1,
    const float* __restrict__ sc0, const float* __restrict__ sc1,
    u16* __restrict__ obf, float* __restrict__ of32,
    int K, int NBN, int ldc)
{
    __shared__ __align__(16) u16 lds[65536];   // 128 KiB

    constexpr int S0 = (EPI == 3) ? 128 : 256;   // B row-block stride per bn
    constexpr int H1 = (EPI == 3) ? 0   : 128;   // row offset of half1 in B1

    const int tid  = threadIdx.x;
    const int lane = tid & 63;
    const int wave = tid >> 6;          // 0..7
    const int wm   = wave >> 2;         // 0..1
    const int wn   = wave & 3;          // 0..3

    // XCD-aware bijective swizzle (m204); bm slow, bn fast (R10)
    const int nwg  = 16 * NBN;
    const int orig = blockIdx.x;
    const int qq   = nwg >> 3, rr = nwg & 7;
    const int xcd  = orig & 7;
    const int swz  = (xcd < rr ? xcd*(qq+1) : rr*(qq+1) + (xcd-rr)*qq) + (orig >> 3);
    const int bm   = swz / NBN;
    const int bn   = swz % NBN;

    // fragment-read per-thread constants (u16-element offsets)
    const int r    = lane & 15;
    const int sQ   = lane >> 4;         // 0..3
    const int x7   = r & 7;
    const int g0E  = (sQ ^ x7) * 8;           // kk=0 granule
    const int g1E  = ((4 | sQ) ^ x7) * 8;     // kk=1 granule
    const int aoffE = (wm*64 + r) * 64;
    const int boffE = (wn*32 + r) * 64;

    // stage per-thread constants (inverse swizzle on the global source)
    const int lrow = lane >> 3;                       // 0..7
    const int goff = ((lane & 7) ^ lrow) * 8;         // elems within 64-col row
    const size_t a_sbase = (size_t)(bm*256 + wave*8 + lrow) * K + goff;
    const u16* b0base = B0 + (size_t)(bn*S0 +      wave*8 + lrow) * K + goff;
    const u16* b1base = B1 + (size_t)(bn*S0 + H1 + wave*8 + lrow) * K + goff;

    f32x4 acc[8][4];
#pragma unroll
    for (int m = 0; m < 8; ++m)
#pragma unroll
        for (int n = 0; n < 4; ++n) acc[m][n] = (f32x4){0.f, 0.f, 0.f, 0.f};

    const int nt = K >> 6;              // K/64: 64 (K=4096) or 172 (K=11008), even

    // ---- prologue: tile0 complete -> buf0 [8]; tile1 {Ah0,Bh0,Bh1} -> buf1 [6]
    STAGE_A(0, 0, 0); STAGE_A(0, 1, 0); STAGE_B(0, 0, 0); STAGE_B(0, 1, 0);
    STAGE_A(1, 0, 64); STAGE_B(1, 0, 64); STAGE_B(1, 1, 64);
    VMC(6);                              // tile0's 8 gloads complete per-wave
    BAR;                                 // all waves' tile0 staging complete

    bf16x8 a0[4][2], a1[4][2], b0[2][2], b1[2][2];

    for (int t = 0; t < nt; t += 2) {
        TILE2(0, 1, t);
        TILE2(1, 0, t + 1);
    }

    // ---- epilogue
    if constexpr (EPI == 3) {
        // fused gate+up: acc[m][n] (gate) pairs with acc[m][n+2] (up), same f
#pragma unroll
        for (int n = 0; n < 2; ++n) {
            const int f = bn*128 + wn*32 + n*16 + r;
            const float gsc = sc0[f];
            const float usc = sc1[f];
#pragma unroll
            for (int m = 0; m < 8; ++m) {
                const int row = bm*256 + (m>>2)*128 + wm*64 + (m&3)*16 + sQ*4;
#pragma unroll
                for (int q = 0; q < 4; ++q) {
                    const float g = acc[m][n][q] * gsc;
                    const float u = acc[m][n+2][q] * usc;
                    const float s2 = g / (1.0f + __expf(-g));
                    obf[(size_t)(row + q) * ldc + f] = bf16_rn(s2 * u);
                }
            }
        }
    } else {
#pragma unroll
        for (int n = 0; n < 4; ++n) {
            const int col = bn*256 + (n>>1)*128 + wn*32 + (n&1)*16 + r;
            const float sc = sc0[col];
#pragma unroll
            for (int m = 0; m < 8; ++m) {
                const int row = bm*256 + (m>>2)*128 + wm*64 + (m&3)*16 + sQ*4;
#pragma unroll
                for (int q = 0; q < 4; ++q) {
                    const float v = acc[m][n][q] * sc;
                    of32[(size_t)(row + q) * ldc + col] = v;
                }
            }
        }
    }
}

extern "C" void kernel_launch(void* const* d_in, const int* in_sizes, int n_in,
                              void* d_out, int out_size, void* d_ws, size_t ws_size,
                              hipStream_t stream) {
    const float* x  = (const float*)d_in[0];
    const int*   gw = (const int*)d_in[1];
    const float* gs = (const float*)d_in[2];
    const int*   uw = (const int*)d_in[3];
    const float* us = (const float*)d_in[4];
    const int*   dw = (const int*)d_in[5];
    const float* ds = (const float*)d_in[6];
    float* out = (float*)d_out;

    const size_t XB = (size_t)NTOK * D_MODEL * 2;   // 33.5 MB  x bf16
    const size_t WB = (size_t)D_FF * D_MODEL * 2;   // 90.2 MB  weight bf16
    const size_t HB = (size_t)NTOK * D_FF * 2;      // 90.2 MB  h bf16
    if (ws_size < XB + 2 * WB + HB) return;         // loud failure (poisoned out)

    char* ws = (char*)d_ws;
    u16* xb  = (u16*)ws;
    u16* wbG = (u16*)(ws + XB);
    u16* wbU = (u16*)(ws + XB + WB);
    u16* hb  = (u16*)(ws + XB + 2 * WB);

    const int wn_elems = D_FF * D_MODEL;            // 45,088,768
    const int wgrid = wn_elems / (8 * 256);

    k_cvt_x<<<(NTOK * D_MODEL) / (8 * 256), 256, 0, stream>>>(x, xb);
    k_cvt_w<<<wgrid, 256, 0, stream>>>(gw, wbG, wn_elems);
    k_cvt_w<<<wgrid, 256, 0, stream>>>(uw, wbU, wn_elems);

    // fused: h = bf16( silu((xb.gw^T)*gs) * (xb.uw^T)*us )
    k_gemm256<3><<<16 * (D_FF / 128), 512, 0, stream>>>(
        xb, wbG, wbU, gs, us, hb, nullptr, D_MODEL, D_FF / 128, D_FF);

    // down: out = (h . dw^T) * ds   (reuse gate-weight buffer)
    k_cvt_w<<<wgrid, 256, 0, stream>>>(dw, wbG, wn_elems);
    k_gemm256<2><<<16 * (D_MODEL / 256), 512, 0, stream>>>(
        hb, wbG, wbG, ds, nullptr, nullptr, out, D_FF, D_MODEL / 256, D_MODEL);
}